// Round 4
// baseline (200.569 us; speedup 1.0000x reference)
//
#include <hip/hip_runtime.h>
#include <hip/hip_bf16.h>

#define PP     512
#define KK     64
#define BB     32
#define LLEN   2048
#define NPOS   (BB * LLEN)   // 65536

typedef __attribute__((ext_vector_type(8)))  short short8;
typedef __attribute__((ext_vector_type(16))) float float16;

__device__ inline unsigned int pack_bf2(float lo, float hi) {
    __hip_bfloat162 h = __float22bfloat162_rn(make_float2(lo, hi));
    unsigned int u;
    __builtin_memcpy(&u, &h, 4);
    return u;   // low 16 = lo, high 16 = hi
}
__device__ inline float bf_lo(unsigned int v) { return __uint_as_float(v << 16); }
__device__ inline float bf_hi(unsigned int v) { return __uint_as_float(v & 0xffff0000u); }

// ---------------------------------------------------------------------------
// K1: unified B-operand fragments, 128 columns: n<64 -> l_hat[n], n>=64 -> f2w[n-64].
// Layout (ushort): Bu[((p>>3)*128 + n)*8 + (p&7)] = bf16(src[n][p] * inv)
// ---------------------------------------------------------------------------
__global__ void k1_prep(const float* __restrict__ C, const float* __restrict__ f2w,
                        ushort* __restrict__ Bu) {
    const int n = blockIdx.x;            // 0..127
    const float* src = (n < 64) ? (C + n * PP) : (f2w + (n - 64) * PP);
    const int t = threadIdx.x;
    float v0 = src[t];
    float v1 = src[t + 256];
    __shared__ float red[256];
    red[t] = v0 * v0 + v1 * v1;
    __syncthreads();
    for (int s = 128; s > 0; s >>= 1) {
        if (t < s) red[t] += red[t + s];
        __syncthreads();
    }
    const float inv = (n < 64) ? rsqrtf(red[0]) : 1.f;
    Bu[(((t >> 3)      * 128 + n) << 3) + (t & 7)] = (ushort)(pack_bf2(v0 * inv, 0.f) & 0xffffu);
    Bu[((((t + 256) >> 3)) * 128 + n) * 8 + (t & 7)] = (ushort)(pack_bf2(v1 * inv, 0.f) & 0xffffu);
}

// ---------------------------------------------------------------------------
// K2: single MFMA GEMM, 64 positions x 128 n-columns, K=512 in 4 chunks of 128.
// Wave w: m-tile (w&1)*32, n-half (w>>1)*64 (two 32-wide MFMAs).
// Outputs: Gt2[pos][j] = pack(cos_j, cos_{j+32}) ; E2p[pos][j] = pack(e.f2w_j, e.f2w_{j+32})
// LDS: sA 16KB xor-swizzled + sB 32KB = ~49.7KB -> 3 blocks/CU.
// ---------------------------------------------------------------------------
__launch_bounds__(256, 3)
__global__ void k2_gemm(const int* __restrict__ x, const float* __restrict__ V,
                        const uint4* __restrict__ Bu4,
                        unsigned int* __restrict__ Gt2, unsigned int* __restrict__ E2p) {
    __shared__ uint4 sA[64 * 16];    // 16 KB
    __shared__ uint4 sB[16 * 128];   // 32 KB
    __shared__ int   stok[64];
    __shared__ float rnorm[64];

    const int tid  = threadIdx.x;
    const int lane = tid & 63;
    const int wv   = tid >> 6;

    if (tid < 64) stok[tid] = x[blockIdx.x * 64 + tid];

    float16 acc0, acc1;
#pragma unroll
    for (int i = 0; i < 16; ++i) { acc0[i] = 0.f; acc1[i] = 0.f; }
    float nacc[4];
#pragma unroll
    for (int i = 0; i < 4; ++i) nacc[i] = 0.f;

    const int mt = (wv & 1) * 32;
    const int nh = (wv >> 1) * 64;

    for (int kc = 0; kc < 4; ++kc) {
        __syncthreads();
        // ---- stage A chunk: 64 pos x 128 p, fp32 norms computed pre-pack ----
#pragma unroll
        for (int i = 0; i < 4; ++i) {
            const int m = (tid >> 4) + i * 16;
            const int f = tid & 15;
            const float* src = V + (size_t)stok[m] * PP + kc * 128 + f * 8;
            const float4 a = ((const float4*)src)[0];
            const float4 b = ((const float4*)src)[1];
            uint4 wq;
            wq.x = pack_bf2(a.x, a.y); wq.y = pack_bf2(a.z, a.w);
            wq.z = pack_bf2(b.x, b.y); wq.w = pack_bf2(b.z, b.w);
            sA[m * 16 + (f ^ (m & 7))] = wq;
            float s2 = 0.f;
            s2 = fmaf(a.x, a.x, s2); s2 = fmaf(a.y, a.y, s2);
            s2 = fmaf(a.z, a.z, s2); s2 = fmaf(a.w, a.w, s2);
            s2 = fmaf(b.x, b.x, s2); s2 = fmaf(b.y, b.y, s2);
            s2 = fmaf(b.z, b.z, s2); s2 = fmaf(b.w, b.w, s2);
            nacc[i] += s2;
        }
        // ---- stage B chunk: 2048 uint4, linear ----
#pragma unroll
        for (int i = 0; i < 8; ++i)
            sB[i * 256 + tid] = Bu4[kc * 2048 + i * 256 + tid];

        if (kc == 3) {
#pragma unroll
            for (int i = 0; i < 4; ++i) {
                float r = nacc[i];
                r += __shfl_down(r, 8, 16);
                r += __shfl_down(r, 4, 16);
                r += __shfl_down(r, 2, 16);
                r += __shfl_down(r, 1, 16);
                if ((tid & 15) == 0) rnorm[(tid >> 4) + i * 16] = rsqrtf(r);
            }
        }
        __syncthreads();

        // ---- MFMA: 8 K-steps of 16 ----
#pragma unroll
        for (int kb = 0; kb < 8; ++kb) {
            const int f  = kb * 2 + (lane >> 5);
            const int mq = mt + (lane & 31);
            const uint4 av = sA[mq * 16 + (f ^ (mq & 7))];
            const uint4 b0 = sB[f * 128 + nh + (lane & 31)];
            const uint4 b1 = sB[f * 128 + nh + 32 + (lane & 31)];
            short8 a8, t0, t1;
            __builtin_memcpy(&a8, &av, 16);
            __builtin_memcpy(&t0, &b0, 16);
            __builtin_memcpy(&t1, &b1, 16);
            acc0 = __builtin_amdgcn_mfma_f32_32x32x16_bf16(a8, t0, acc0, 0, 0, 0);
            acc1 = __builtin_amdgcn_mfma_f32_32x32x16_bf16(a8, t1, acc1, 0, 0, 0);
        }
    }

    // ---- epilogue ----
    const size_t posBase = (size_t)blockIdx.x * 64;
#pragma unroll
    for (int reg = 0; reg < 16; ++reg) {
        const int r  = (reg & 3) + 8 * (reg >> 2) + 4 * (lane >> 5);
        const int mq = mt + r;
        const size_t p = posBase + mq;
        if (wv < 2) {
            const float rn = rnorm[mq];
            Gt2[p * 32 + (lane & 31)] = pack_bf2(acc0[reg] * rn, acc1[reg] * rn);
        } else {
            E2p[p * 32 + (lane & 31)] = pack_bf2(acc0[reg], acc1[reg]);
        }
    }
}

// ---------------------------------------------------------------------------
// K3: mm[b][l] = max_k relu(conv11(G)[l] + f1b[k]), packed-bf16 Gt2 input.
// Block: one b, 128 l. LDS tile 138 x 32 uints, +1 pad stride.
// ---------------------------------------------------------------------------
__global__ void k3_convmax(const unsigned int* __restrict__ Gt2, const float* __restrict__ f1w,
                           const float* __restrict__ f1b, float* __restrict__ mm) {
    __shared__ unsigned int sT[138 * 33];
    const int b  = blockIdx.x >> 4;
    const int l0 = (blockIdx.x & 15) * 128;
    const int t  = threadIdx.x;
    for (int idx = t; idx < 138 * 32; idx += 256) {
        const int row = idx >> 5, col = idx & 31;
        const int gl = l0 - 5 + row;
        sT[row * 33 + col] = (gl >= 0 && gl < LLEN)
            ? Gt2[((size_t)b * LLEN + gl) * 32 + col] : 0u;
    }
    __syncthreads();
    float w[11];
#pragma unroll
    for (int j = 0; j < 11; ++j) w[j] = f1w[j];
    const int j = t & 31;
    const int h = t >> 5;
    const float bias0 = f1b[j], bias1 = f1b[j + 32];
#pragma unroll 2
    for (int i = 0; i < 16; ++i) {
        const int lr = i * 8 + h;
        float u0 = 0.f, u1 = 0.f;
#pragma unroll
        for (int tap = 0; tap < 11; ++tap) {
            const unsigned int v = sT[(lr + tap) * 33 + j];
            u0 = fmaf(bf_lo(v), w[tap], u0);
            u1 = fmaf(bf_hi(v), w[tap], u1);
        }
        float m = fmaxf(fmaxf(u0 + bias0, 0.f), fmaxf(u1 + bias1, 0.f));
#pragma unroll
        for (int off = 16; off > 0; off >>= 1)
            m = fmaxf(m, __shfl_xor(m, off, 64));
        if (j == 0) mm[b * LLEN + l0 + lr] = m;
    }
}

// ---------------------------------------------------------------------------
// K7: fused softmax + pooled head. Block = one b (32 blocks).
//   beta = softmax(mm[b]); out[b][k] = (1/L) sum_l beta[l]*E2[l][k] + f2b[k]
// ---------------------------------------------------------------------------
__global__ void k7_softpool(const float* __restrict__ mm, const unsigned int* __restrict__ E2p,
                            const float* __restrict__ f2b, float* __restrict__ out) {
    const int b = blockIdx.x;
    const int t = threadIdx.x;
    __shared__ float red[256];
    __shared__ float sbeta[LLEN];
    __shared__ float sred[8][64];

    float v[8];
    float mx = -1e30f;
#pragma unroll
    for (int i = 0; i < 8; ++i) {
        v[i] = mm[b * LLEN + t + i * 256];
        mx = fmaxf(mx, v[i]);
    }
    red[t] = mx;
    __syncthreads();
    for (int s = 128; s > 0; s >>= 1) {
        if (t < s) red[t] = fmaxf(red[t], red[t + s]);
        __syncthreads();
    }
    mx = red[0];
    __syncthreads();
    float sm = 0.f;
#pragma unroll
    for (int i = 0; i < 8; ++i) {
        v[i] = __expf(v[i] - mx);
        sm += v[i];
    }
    red[t] = sm;
    __syncthreads();
    for (int s = 128; s > 0; s >>= 1) {
        if (t < s) red[t] += red[t + s];
        __syncthreads();
    }
    const float inv = 1.f / red[0];
#pragma unroll
    for (int i = 0; i < 8; ++i) sbeta[t + i * 256] = v[i] * inv;
    __syncthreads();

    // pooling: lane-pair j covers k=j and k=j+32; h-group strides l
    const int j = t & 31, h = t >> 5;
    float a0 = 0.f, a1 = 0.f;
#pragma unroll 8
    for (int i = 0; i < 256; ++i) {
        const int l = i * 8 + h;
        const float wgt = sbeta[l];
        const unsigned int e = E2p[((size_t)b * LLEN + l) * 32 + j];
        a0 = fmaf(wgt, bf_lo(e), a0);
        a1 = fmaf(wgt, bf_hi(e), a1);
    }
    sred[h][j]      = a0;
    sred[h][j + 32] = a1;
    __syncthreads();
    if (t < 64) {
        float r = 0.f;
#pragma unroll
        for (int hh = 0; hh < 8; ++hh) r += sred[hh][t];
        out[b * KK + t] = r * (1.f / 2048.f) + f2b[t];
    }
}

extern "C" void kernel_launch(void* const* d_in, const int* in_sizes, int n_in,
                              void* d_out, int out_size, void* d_ws, size_t ws_size,
                              hipStream_t stream) {
    const int*   x   = (const int*)d_in[0];
    const float* V   = (const float*)d_in[1];
    const float* C   = (const float*)d_in[2];
    const float* f1w = (const float*)d_in[3];
    const float* f1b = (const float*)d_in[4];
    const float* f2w = (const float*)d_in[5];
    const float* f2b = (const float*)d_in[6];
    float* out = (float*)d_out;

    float* ws = (float*)d_ws;
    ushort* Bu = (ushort*)ws;                             // 512*128 ushort = 32768 floats... (16384 fl)
    unsigned int* Gt2 = (unsigned int*)(ws + 32768);      // NPOS*32 uints
    unsigned int* E2p = Gt2 + (size_t)NPOS * 32;          // NPOS*32 uints
    float* mm = (float*)(E2p + (size_t)NPOS * 32);        // NPOS floats

    k1_prep    <<<128, 256, 0, stream>>>(C, f2w, Bu);
    k2_gemm    <<<NPOS / 64, 256, 0, stream>>>(x, V, (const uint4*)Bu, Gt2, E2p);
    k3_convmax <<<BB * (LLEN / 128), 256, 0, stream>>>(Gt2, f1w, f1b, mm);
    k7_softpool<<<BB, 256, 0, stream>>>(mm, E2p, f2b, out);
}